// Round 1
// baseline (1391.873 us; speedup 1.0000x reference)
//
#include <hip/hip_runtime.h>

typedef float f32x4 __attribute__((ext_vector_type(4)));
typedef __bf16 bf16x8 __attribute__((ext_vector_type(8)));
typedef unsigned short ushort;
typedef ushort ushort8 __attribute__((ext_vector_type(8)));
typedef ushort ushort4v __attribute__((ext_vector_type(4)));

#define DM 1024
#define DI 2048
#define DSTATE 128
#define NH 32
#define HD 64
#define CONVDIM 2304
#define DPROJ 4384
#define ROWS 8192

__device__ __forceinline__ float bf2f(ushort u){
  union { unsigned int i; float f; } v; v.i = ((unsigned int)u)<<16; return v.f;
}
__device__ __forceinline__ ushort f2bf(float f){
  union { float f; unsigned int i; } v; v.f = f;
  unsigned int r = v.i + 0x7FFFu + ((v.i>>16)&1u);
  return (ushort)(r>>16);
}
__device__ __forceinline__ float siluf(float x){ return x / (1.f + __expf(-x)); }

__device__ __forceinline__ void gload16(const ushort* g, ushort* l){
  __builtin_amdgcn_global_load_lds(
      (const __attribute__((address_space(1))) void*)g,
      (__attribute__((address_space(3))) void*)l, 16, 0, 0);
}

// ---------------- elementwise: Ya = bf16(silu(y)) ----------------
__global__ __launch_bounds__(256) void k_silu_cast(const float* __restrict__ in,
                                                   ushort* __restrict__ out, int n){
  int i = (blockIdx.x*256 + threadIdx.x)*4;
  if (i >= n) return;
  float4 v = *(const float4*)(in + i);
  ushort4v o;
  o.x = f2bf(siluf(v.x)); o.y = f2bf(siluf(v.y));
  o.z = f2bf(siluf(v.z)); o.w = f2bf(siluf(v.w));
  *(ushort4v*)(out + i) = o;
}

// ---------------- weight transpose+cast: in[K][N] f32 -> out[N][K] bf16 ----------------
__global__ __launch_bounds__(256) void k_transpose_cast(const float* __restrict__ in,
                                                        ushort* __restrict__ out,
                                                        int K, int N){
  __shared__ float tile[32][33];
  int n0 = blockIdx.x*32, k0 = blockIdx.y*32;
  int tx = threadIdx.x & 31, ty = threadIdx.x >> 5; // 32x8
  for (int r = ty; r < 32; r += 8) tile[r][tx] = in[(size_t)(k0+r)*N + n0+tx];
  __syncthreads();
  for (int r = ty; r < 32; r += 8) out[(size_t)(n0+r)*K + k0+tx] = f2bf(tile[tx][r]);
}

// ---------------- at[b][n] = silu(t[b]) @ w_ada + b_ada ----------------
__global__ __launch_bounds__(256) void k_at(const float* __restrict__ t,
                                            const float* __restrict__ w_ada,
                                            const float* __restrict__ b_ada,
                                            float* __restrict__ at){
  __shared__ float st[1024];
  int b = blockIdx.y;
  int col = blockIdx.x*256 + threadIdx.x;
  for (int i = threadIdx.x; i < 1024; i += 256) st[i] = siluf(t[b*1024 + i]);
  __syncthreads();
  float acc = 0.f;
  for (int k = 0; k < 1024; ++k) acc += st[k] * w_ada[(size_t)k*3072 + col];
  at[b*3072 + col] = acc + b_ada[col];
}

// ---------------- GEMM: A[M][K] bf16 row-major, Bt[N][K] bf16 row-major ----------------
// EPI 0: Cb bf16 = acc                    (in_proj -> zxbcdt)
// EPI 1: Cb bf16 = acc + bias[n] + at[b][n]   (ada -> M buffer)
// EPI 2: Cf f32  = gate[row,n]*acc + x[row,n] (out_proj -> d_out)
template<int EPI>
__global__ __launch_bounds__(256)
void k_gemm(const ushort* __restrict__ A, const ushort* __restrict__ Bt,
            ushort* __restrict__ Cb, float* __restrict__ Cf,
            int M, int N, int K, int ldc,
            const float* __restrict__ bias, const float* __restrict__ at,
            const ushort* __restrict__ gateM, const float* __restrict__ xres){
  __shared__ __align__(16) ushort lA[128*32];
  __shared__ __align__(16) ushort lB[128*32];
  const int tid  = threadIdx.x;
  const int wave = tid >> 6, lane = tid & 63;
  const int bn = blockIdx.x, bm = blockIdx.y;
  const int wr = wave >> 1, wc = wave & 1;
  const int l16 = lane & 15, kb = lane >> 4;
  // staging map: chunk = (wave*2+i)*64 + lane ; row = chunk>>2 ; kc = chunk&3
  const int arow0 = (wave*2+0)*16 + (lane>>2);
  const int arow1 = (wave*2+1)*16 + (lane>>2);
  const int kc = lane & 3;

  f32x4 acc[4][4];
#pragma unroll
  for (int m=0;m<4;m++)
#pragma unroll
    for (int n=0;n<4;n++) acc[m][n] = (f32x4){0.f,0.f,0.f,0.f};

  for (int k0 = 0; k0 < K; k0 += 32){
    __syncthreads();
    {
      gload16(A + (size_t)(bm*128 + arow0)*K + k0 + kc*8, &lA[(wave*2+0)*512]);
      gload16(A + (size_t)(bm*128 + arow1)*K + k0 + kc*8, &lA[(wave*2+1)*512]);
      int br0 = bn*128 + arow0; if (br0 > N-1) br0 = N-1;
      int br1 = bn*128 + arow1; if (br1 > N-1) br1 = N-1;
      gload16(Bt + (size_t)br0*K + k0 + kc*8, &lB[(wave*2+0)*512]);
      gload16(Bt + (size_t)br1*K + k0 + kc*8, &lB[(wave*2+1)*512]);
    }
    __syncthreads();
    bf16x8 af[4], bfr[4];
#pragma unroll
    for (int m=0;m<4;m++) af[m]  = *(const bf16x8*)&lA[(wr*64 + m*16 + l16)*32 + kb*8];
#pragma unroll
    for (int n=0;n<4;n++) bfr[n] = *(const bf16x8*)&lB[(wc*64 + n*16 + l16)*32 + kb*8];
#pragma unroll
    for (int m=0;m<4;m++)
#pragma unroll
      for (int n=0;n<4;n++)
        acc[m][n] = __builtin_amdgcn_mfma_f32_16x16x32_bf16(af[m], bfr[n], acc[m][n], 0, 0, 0);
  }

#pragma unroll
  for (int m=0;m<4;m++){
    int grow_base = bm*128 + wr*64 + m*16 + (lane>>4)*4;
#pragma unroll
    for (int n=0;n<4;n++){
      int gcol = bn*128 + wc*64 + n*16 + l16;
      if (EPI == 0){
        if (gcol < N){
#pragma unroll
          for (int r=0;r<4;r++) Cb[(size_t)(grow_base+r)*ldc + gcol] = f2bf(acc[m][n][r]);
        }
      } else if (EPI == 1){
        float bv = bias[gcol];
#pragma unroll
        for (int r=0;r<4;r++){
          int row = grow_base + r;
          float v = acc[m][n][r] + bv + at[(row>>10)*3072 + gcol];
          Cb[(size_t)row*ldc + gcol] = f2bf(v);
        }
      } else {
#pragma unroll
        for (int r=0;r<4;r++){
          int row = grow_base + r;
          float g = bf2f(gateM[(size_t)row*3072 + 2048 + gcol]);
          Cf[(size_t)row*ldc + gcol] = g*acc[m][n][r] + xres[(size_t)row*1024 + gcol];
        }
      }
    }
  }
}

// ---------------- LN + modulation: mod = LN(x)*(1+scale)+shift (bf16) ----------------
__global__ __launch_bounds__(256) void k_lnmod(const float* __restrict__ x,
                                               const ushort* __restrict__ Mb,
                                               ushort* __restrict__ mod){
  int row = blockIdx.x;
  const float* xr = x + (size_t)row*1024;
  float v[4]; float s = 0.f, s2 = 0.f;
#pragma unroll
  for (int j=0;j<4;j++){ v[j] = xr[threadIdx.x + j*256]; s += v[j]; s2 += v[j]*v[j]; }
#pragma unroll
  for (int o=32;o>0;o>>=1){ s += __shfl_down(s,o); s2 += __shfl_down(s2,o); }
  __shared__ float ls[4], ls2[4];
  int wv = threadIdx.x >> 6;
  if ((threadIdx.x & 63) == 0){ ls[wv] = s; ls2[wv] = s2; }
  __syncthreads();
  s  = ls[0]+ls[1]+ls[2]+ls[3];
  s2 = ls2[0]+ls2[1]+ls2[2]+ls2[3];
  float mu = s * (1.f/1024.f);
  float var = s2 * (1.f/1024.f) - mu*mu;
  float rstd = rsqrtf(var + 1e-6f);
  const ushort* Mr = Mb + (size_t)row*3072;
#pragma unroll
  for (int j=0;j<4;j++){
    int d = threadIdx.x + j*256;
    float sc = bf2f(Mr[1024 + d]);
    float sh = bf2f(Mr[d]);
    mod[(size_t)row*1024 + d] = f2bf((v[j]-mu)*rstd*(1.f+sc) + sh);
  }
}

// ---------------- causal conv4 + silu over xBC cols [2048,4352) of zx ----------------
__global__ __launch_bounds__(256) void k_conv(const ushort* __restrict__ zx,
                                              const float* __restrict__ conv_w,
                                              const float* __restrict__ conv_b,
                                              ushort* __restrict__ co){
  int ch  = blockIdx.x*256 + threadIdx.x;   // < 2304
  int row = blockIdx.y;                      // < 8192
  int l = row & 1023, b = row >> 10;
  float acc = conv_b[ch];
#pragma unroll
  for (int k=0;k<4;k++){
    int ll = l - 3 + k;
    if (ll >= 0) acc += conv_w[ch*4 + k] * bf2f(zx[(size_t)(b*1024 + ll)*DPROJ + 2048 + ch]);
  }
  co[(size_t)row*CONVDIM + ch] = f2bf(siluf(acc));
}

// ---------------- dt prep: dt_soft = softplus(dt+dt_bias), dA = exp(dt_soft*-exp(A_log)) ----------------
__global__ __launch_bounds__(256) void k_dt(const ushort* __restrict__ zx,
                                            const float* __restrict__ dt_bias,
                                            const float* __restrict__ A_log,
                                            float* __restrict__ dtb, float* __restrict__ dAb){
  int i = blockIdx.x*256 + threadIdx.x;      // < 8192*32
  int h = i & 31, row = i >> 5;
  float d = bf2f(zx[(size_t)row*DPROJ + 4352 + h]) + dt_bias[h];
  float sp = (d > 20.f) ? d : log1pf(__expf(d));
  float A = -__expf(A_log[h]);
  dtb[i] = sp;
  dAb[i] = __expf(sp * A);
}

// ---------------- SSM scan: one block per (b,h), 512 threads, state in regs ----------------
__global__ __launch_bounds__(512) void k_scan(const ushort* __restrict__ co,
                                              const ushort* __restrict__ zx,
                                              const float* __restrict__ dtb,
                                              const float* __restrict__ dAb,
                                              const float* __restrict__ Dp_,
                                              ushort* __restrict__ yv){
  int b = blockIdx.x >> 5, h = blockIdx.x & 31;
  int t = threadIdx.x, p = t >> 3, g = t & 7;   // 64 p x 8 groups of 16 n
  float hs[16];
#pragma unroll
  for (int j=0;j<16;j++) hs[j] = 0.f;
  float Dp = Dp_[h];
  const ushort* cb = co + (size_t)(b*1024)*CONVDIM;
  for (int l=0; l<1024; ++l){
    const ushort* rowp = cb + (size_t)l*CONVDIM;
    int row = b*1024 + l;
    float dA = dAb[row*32 + h];
    float dt = dtb[row*32 + h];
    float xh = bf2f(rowp[h*64 + p]);
    float dtx = dt * xh;
    ushort8 Bv0 = *(const ushort8*)&rowp[2048 + g*16];
    ushort8 Bv1 = *(const ushort8*)&rowp[2048 + g*16 + 8];
    ushort8 Cv0 = *(const ushort8*)&rowp[2176 + g*16];
    ushort8 Cv1 = *(const ushort8*)&rowp[2176 + g*16 + 8];
    float acc = 0.f;
#pragma unroll
    for (int j=0;j<8;j++){
      hs[j] = hs[j]*dA + dtx*bf2f(Bv0[j]);
      acc  += hs[j]*bf2f(Cv0[j]);
    }
#pragma unroll
    for (int j=0;j<8;j++){
      hs[8+j] = hs[8+j]*dA + dtx*bf2f(Bv1[j]);
      acc    += hs[8+j]*bf2f(Cv1[j]);
    }
    acc += __shfl_xor(acc, 1);
    acc += __shfl_xor(acc, 2);
    acc += __shfl_xor(acc, 4);
    if (g == 0){
      float yo = acc + Dp*xh;
      float z  = bf2f(zx[(size_t)row*DPROJ + h*64 + p]);
      yv[(size_t)row*DI + h*64 + p] = f2bf(yo * siluf(z));
    }
  }
}

extern "C" void kernel_launch(void* const* d_in, const int* in_sizes, int n_in,
                              void* d_out, int out_size, void* d_ws, size_t ws_size,
                              hipStream_t stream){
  const float* x       = (const float*)d_in[0];
  const float* t       = (const float*)d_in[1];
  const float* y       = (const float*)d_in[2];
  const float* w_ada   = (const float*)d_in[3];
  const float* b_ada   = (const float*)d_in[4];
  const float* w_in    = (const float*)d_in[5];
  const float* conv_w  = (const float*)d_in[6];
  const float* conv_b  = (const float*)d_in[7];
  const float* dt_bias = (const float*)d_in[8];
  const float* A_log   = (const float*)d_in[9];
  const float* D_param = (const float*)d_in[10];
  const float* w_out   = (const float*)d_in[11];

  char* w = (char*)d_ws;
  size_t off = 0;
  auto alloc = [&](size_t bytes)->char*{
    char* p = w + off; off += (bytes + 255) & ~(size_t)255; return p;
  };
  ushort* waT   = (ushort*)alloc(3072ull*1024*2);
  ushort* winT  = (ushort*)alloc(4384ull*1024*2);
  ushort* woutT = (ushort*)alloc(1024ull*2048*2);
  float*  atb   = (float*) alloc(8ull*3072*4);
  ushort* Ya    = (ushort*)alloc((size_t)ROWS*1024*2);  // reused as `mod` after ada GEMM
  ushort* Mb    = (ushort*)alloc((size_t)ROWS*3072*2);
  ushort* zx    = (ushort*)alloc((size_t)ROWS*DPROJ*2);
  ushort* co    = (ushort*)alloc((size_t)ROWS*CONVDIM*2);
  float*  dtb   = (float*) alloc((size_t)ROWS*32*4);
  float*  dAb   = (float*) alloc((size_t)ROWS*32*4);
  ushort* yv    = (ushort*)alloc((size_t)ROWS*DI*2);

  // 1. Ya = bf16(silu(y))
  k_silu_cast<<<dim3(ROWS*1024/(256*4)), 256, 0, stream>>>(y, Ya, ROWS*1024);
  // 2. weight transposes (f32 -> bf16 [N][K])
  k_transpose_cast<<<dim3(96,32),  256, 0, stream>>>(w_ada, waT,  1024, 3072);
  k_transpose_cast<<<dim3(137,32), 256, 0, stream>>>(w_in,  winT, 1024, 4384);
  k_transpose_cast<<<dim3(32,64),  256, 0, stream>>>(w_out, woutT, 2048, 1024);
  // 3. at = silu(t)@w_ada + b_ada  (f32)
  k_at<<<dim3(12,8), 256, 0, stream>>>(t, w_ada, b_ada, atb);
  // 4. Mb = silu(y)@w_ada + b_ada + at[b]   (shift|scale|gate)
  k_gemm<1><<<dim3(24,64), 256, 0, stream>>>(Ya, waT, Mb, nullptr, ROWS, 3072, 1024, 3072,
                                             b_ada, atb, nullptr, nullptr);
  // 5. mod = LN(x)*(1+scale)+shift  (into Ya)
  k_lnmod<<<dim3(ROWS), 256, 0, stream>>>(x, Mb, Ya);
  // 6. zx = mod @ w_in
  k_gemm<0><<<dim3(35,64), 256, 0, stream>>>(Ya, winT, zx, nullptr, ROWS, DPROJ, 1024, DPROJ,
                                             nullptr, nullptr, nullptr, nullptr);
  // 7. conv4 + silu
  k_conv<<<dim3(9,ROWS), 256, 0, stream>>>(zx, conv_w, conv_b, co);
  // 8. dt prep
  k_dt<<<dim3(ROWS*32/256), 256, 0, stream>>>(zx, dt_bias, A_log, dtb, dAb);
  // 9. SSM scan -> yv (includes D*xh and silu(z) gating)
  k_scan<<<dim3(256), 512, 0, stream>>>(co, zx, dtb, dAb, D_param, yv);
  // 10. out = gate * (yv @ w_out) + x
  k_gemm<2><<<dim3(8,64), 256, 0, stream>>>(yv, woutT, nullptr, (float*)d_out, ROWS, 1024, 2048, 1024,
                                            nullptr, nullptr, Mb, x);
}

// Round 3
// 566.071 us; speedup vs baseline: 2.4588x; 2.4588x over previous
//
#include <hip/hip_runtime.h>

typedef float f32x4 __attribute__((ext_vector_type(4)));
typedef __bf16 bf16x8 __attribute__((ext_vector_type(8)));
typedef unsigned short ushort;
typedef ushort ushort8 __attribute__((ext_vector_type(8)));
typedef ushort ushort4v __attribute__((ext_vector_type(4)));

#define DM 1024
#define DI 2048
#define DSTATE 128
#define NH 32
#define HD 64
#define CONVDIM 2304
#define DPROJ 4384
#define ROWS 8192

__device__ __forceinline__ float bf2f(ushort u){
  union { unsigned int i; float f; } v; v.i = ((unsigned int)u)<<16; return v.f;
}
__device__ __forceinline__ ushort f2bf(float f){
  union { float f; unsigned int i; } v; v.f = f;
  unsigned int r = v.i + 0x7FFFu + ((v.i>>16)&1u);
  return (ushort)(r>>16);
}
__device__ __forceinline__ float siluf(float x){ return x / (1.f + __expf(-x)); }

__device__ __forceinline__ void gload16(const ushort* g, ushort* l){
  __builtin_amdgcn_global_load_lds(
      (const __attribute__((address_space(1))) void*)g,
      (__attribute__((address_space(3))) void*)l, 16, 0, 0);
}

// ---------------- elementwise: Ya = bf16(silu(y)) ----------------
__global__ __launch_bounds__(256) void k_silu_cast(const float* __restrict__ in,
                                                   ushort* __restrict__ out, int n){
  int i = (blockIdx.x*256 + threadIdx.x)*4;
  if (i >= n) return;
  float4 v = *(const float4*)(in + i);
  ushort4v o;
  o.x = f2bf(siluf(v.x)); o.y = f2bf(siluf(v.y));
  o.z = f2bf(siluf(v.z)); o.w = f2bf(siluf(v.w));
  *(ushort4v*)(out + i) = o;
}

// ---------------- weight transpose+cast: in[K][N] f32 -> out[N][K] bf16 ----------------
__global__ __launch_bounds__(256) void k_transpose_cast(const float* __restrict__ in,
                                                        ushort* __restrict__ out,
                                                        int K, int N){
  __shared__ float tile[32][33];
  int n0 = blockIdx.x*32, k0 = blockIdx.y*32;
  int tx = threadIdx.x & 31, ty = threadIdx.x >> 5; // 32x8
  for (int r = ty; r < 32; r += 8) tile[r][tx] = in[(size_t)(k0+r)*N + n0+tx];
  __syncthreads();
  for (int r = ty; r < 32; r += 8) out[(size_t)(n0+r)*K + k0+tx] = f2bf(tile[tx][r]);
}

// ---------------- at[b][n] = silu(t[b]) @ w_ada + b_ada ----------------
__global__ __launch_bounds__(256) void k_at(const float* __restrict__ t,
                                            const float* __restrict__ w_ada,
                                            const float* __restrict__ b_ada,
                                            float* __restrict__ at){
  __shared__ float st[1024];
  int b = blockIdx.y;
  int col = blockIdx.x*256 + threadIdx.x;
  for (int i = threadIdx.x; i < 1024; i += 256) st[i] = siluf(t[b*1024 + i]);
  __syncthreads();
  float acc = 0.f;
  for (int k = 0; k < 1024; ++k) acc += st[k] * w_ada[(size_t)k*3072 + col];
  at[b*3072 + col] = acc + b_ada[col];
}

// ---------------- GEMM: A[M][K] bf16 row-major, Bt[N][K] bf16 row-major ----------------
// EPI 0: in_proj -> zz (cols<2048), xbc (2048..4352), dtc (4352..)
// EPI 1: ada -> Mss (cols<2048: shift|scale), Mg (cols>=2048: gate)
// EPI 2: Cf f32 = gate[row,n]*acc + x[row,n]
template<int EPI>
__global__ __launch_bounds__(256)
void k_gemm(const ushort* __restrict__ A, const ushort* __restrict__ Bt,
            ushort* __restrict__ Cb, ushort* __restrict__ Cb2, ushort* __restrict__ Cb3,
            float* __restrict__ Cf,
            int M, int N, int K,
            const float* __restrict__ bias, const float* __restrict__ at,
            const ushort* __restrict__ gateM, const float* __restrict__ xres){
  __shared__ __align__(16) ushort lA[128*32];
  __shared__ __align__(16) ushort lB[128*32];
  const int tid  = threadIdx.x;
  const int wave = tid >> 6, lane = tid & 63;
  const int bn = blockIdx.x, bm = blockIdx.y;
  const int wr = wave >> 1, wc = wave & 1;
  const int l16 = lane & 15, kb = lane >> 4;
  const int arow0 = (wave*2+0)*16 + (lane>>2);
  const int arow1 = (wave*2+1)*16 + (lane>>2);
  const int kc = lane & 3;

  f32x4 acc[4][4];
#pragma unroll
  for (int m=0;m<4;m++)
#pragma unroll
    for (int n=0;n<4;n++) acc[m][n] = (f32x4){0.f,0.f,0.f,0.f};

  for (int k0 = 0; k0 < K; k0 += 32){
    __syncthreads();
    {
      gload16(A + (size_t)(bm*128 + arow0)*K + k0 + kc*8, &lA[(wave*2+0)*512]);
      gload16(A + (size_t)(bm*128 + arow1)*K + k0 + kc*8, &lA[(wave*2+1)*512]);
      int br0 = bn*128 + arow0; if (br0 > N-1) br0 = N-1;
      int br1 = bn*128 + arow1; if (br1 > N-1) br1 = N-1;
      gload16(Bt + (size_t)br0*K + k0 + kc*8, &lB[(wave*2+0)*512]);
      gload16(Bt + (size_t)br1*K + k0 + kc*8, &lB[(wave*2+1)*512]);
    }
    __syncthreads();
    bf16x8 af[4], bfr[4];
#pragma unroll
    for (int m=0;m<4;m++) af[m]  = *(const bf16x8*)&lA[(wr*64 + m*16 + l16)*32 + kb*8];
#pragma unroll
    for (int n=0;n<4;n++) bfr[n] = *(const bf16x8*)&lB[(wc*64 + n*16 + l16)*32 + kb*8];
#pragma unroll
    for (int m=0;m<4;m++)
#pragma unroll
      for (int n=0;n<4;n++)
        acc[m][n] = __builtin_amdgcn_mfma_f32_16x16x32_bf16(af[m], bfr[n], acc[m][n], 0, 0, 0);
  }

#pragma unroll
  for (int m=0;m<4;m++){
    int grow_base = bm*128 + wr*64 + m*16 + (lane>>4)*4;
#pragma unroll
    for (int n=0;n<4;n++){
      int gcol = bn*128 + wc*64 + n*16 + l16;
      if (EPI == 0){
        if (gcol < N){
#pragma unroll
          for (int r=0;r<4;r++){
            int row = grow_base + r;
            float v = acc[m][n][r];
            if (gcol < 2048)      Cb [(size_t)row*2048 + gcol] = f2bf(v);
            else if (gcol < 4352) Cb2[(size_t)row*2304 + (gcol-2048)] = f2bf(v);
            else                  Cb3[(size_t)row*32   + (gcol-4352)] = f2bf(v);
          }
        }
      } else if (EPI == 1){
        float bv = bias[gcol];
#pragma unroll
        for (int r=0;r<4;r++){
          int row = grow_base + r;
          float v = acc[m][n][r] + bv + at[(row>>10)*3072 + gcol];
          if (gcol < 2048) Cb [(size_t)row*2048 + gcol] = f2bf(v);
          else             Cb2[(size_t)row*1024 + (gcol - 2048)] = f2bf(v);
        }
      } else {
#pragma unroll
        for (int r=0;r<4;r++){
          int row = grow_base + r;
          float g = bf2f(gateM[(size_t)row*1024 + gcol]);
          Cf[(size_t)row*1024 + gcol] = g*acc[m][n][r] + xres[(size_t)row*1024 + gcol];
        }
      }
    }
  }
}

// ---------------- LN + modulation: mod = LN(x)*(1+scale)+shift (bf16) ----------------
__global__ __launch_bounds__(256) void k_lnmod(const float* __restrict__ x,
                                               const ushort* __restrict__ Mss,
                                               ushort* __restrict__ mod){
  int row = blockIdx.x;
  const float* xr = x + (size_t)row*1024;
  float v[4]; float s = 0.f, s2 = 0.f;
#pragma unroll
  for (int j=0;j<4;j++){ v[j] = xr[threadIdx.x + j*256]; s += v[j]; s2 += v[j]*v[j]; }
#pragma unroll
  for (int o=32;o>0;o>>=1){ s += __shfl_down(s,o); s2 += __shfl_down(s2,o); }
  __shared__ float ls[4], ls2[4];
  int wv = threadIdx.x >> 6;
  if ((threadIdx.x & 63) == 0){ ls[wv] = s; ls2[wv] = s2; }
  __syncthreads();
  s  = ls[0]+ls[1]+ls[2]+ls[3];
  s2 = ls2[0]+ls2[1]+ls2[2]+ls2[3];
  float mu = s * (1.f/1024.f);
  float var = s2 * (1.f/1024.f) - mu*mu;
  float rstd = rsqrtf(var + 1e-6f);
  const ushort* Mr = Mss + (size_t)row*2048;
#pragma unroll
  for (int j=0;j<4;j++){
    int d = threadIdx.x + j*256;
    float sc = bf2f(Mr[1024 + d]);
    float sh = bf2f(Mr[d]);
    mod[(size_t)row*1024 + d] = f2bf((v[j]-mu)*rstd*(1.f+sc) + sh);
  }
}

// ---------------- causal conv4 + silu over xbc ----------------
__global__ __launch_bounds__(256) void k_conv(const ushort* __restrict__ xbc,
                                              const float* __restrict__ conv_w,
                                              const float* __restrict__ conv_b,
                                              ushort* __restrict__ co){
  int ch  = blockIdx.x*256 + threadIdx.x;   // < 2304
  int row = blockIdx.y;                      // < 8192
  int l = row & 1023, b = row >> 10;
  float acc = conv_b[ch];
#pragma unroll
  for (int k=0;k<4;k++){
    int ll = l - 3 + k;
    if (ll >= 0) acc += conv_w[ch*4 + k] * bf2f(xbc[(size_t)(b*1024 + ll)*CONVDIM + ch]);
  }
  co[(size_t)row*CONVDIM + ch] = f2bf(siluf(acc));
}

// ---------------- transpose co cols [0,2176) -> xhT [b*2048+c][l], BTg [b*128+n][l] ----------------
__global__ __launch_bounds__(256) void k_transT(const ushort* __restrict__ co,
                                                ushort* __restrict__ xhT,
                                                ushort* __restrict__ BTg){
  __shared__ ushort tile[64*72];
  const int c0 = blockIdx.x*64, l0 = blockIdx.y*64, b = blockIdx.z;
  const int tid = threadIdx.x;
  for (int q = tid; q < 512; q += 256){
    int r = q >> 3, cc = q & 7;
    ushort8 v = *(const ushort8*)(co + (size_t)(b*1024 + l0 + r)*CONVDIM + c0 + cc*8);
    *(ushort8*)&tile[r*72 + cc*8] = v;
  }
  __syncthreads();
  for (int q = tid; q < 1024; q += 256){
    int oc = q >> 4, lc = (q & 15)*4;
    ushort4v o;
#pragma unroll
    for (int j = 0; j < 4; ++j) o[j] = tile[(lc + j)*72 + oc];
    int ccol = c0 + oc;
    ushort* out = (ccol < 2048) ? (xhT + (size_t)(b*2048 + ccol)*1024)
                                : (BTg + (size_t)(b*128 + (ccol - 2048))*1024);
    *(ushort4v*)(out + l0 + lc) = o;
  }
}

// ---------------- chunk state contribution: Sc[p][n] = sum_s G[s]*x[s,p]*B[s,n] ----------------
__global__ __launch_bounds__(256) void k_chunkstate(
    const ushort* __restrict__ xhT, const ushort* __restrict__ BTg,
    const ushort* __restrict__ dtc,
    const float* __restrict__ dt_bias, const float* __restrict__ A_log,
    ushort* __restrict__ Sc, float* __restrict__ Dcb){
  __shared__ __align__(16) ushort sXG[64*128];   // 16KB (swizzled)
  __shared__ __align__(16) ushort sBT[128*128];  // 32KB (swizzled)
  __shared__ float sG[128];
  const int bid = blockIdx.x;
  const int h = bid & 31, bc = bid >> 5, b = bc >> 3, c = bc & 7;
  const int tid = threadIdx.x, wave = tid >> 6, lane = tid & 63;
  const int l16 = lane & 15, l4 = lane >> 4;
  const int sci = (b*32 + h)*8 + c;
  {
    const ushort* src = BTg + (size_t)(b*128)*1024 + c*128;
    for (int i2 = 0; i2 < 8; ++i2){
      int itg = wave*8 + i2;
      int r = itg*4 + l4;
      int cc = l16 ^ (r & 7);
      gload16(src + (size_t)r*1024 + cc*8, &sBT[itg*512]);
    }
  }
  const float Ah = -__expf(A_log[h]);
  if (wave == 0){
    const int row0 = b*1024 + c*128;
    float bi = dt_bias[h];
    float d0 = bf2f(dtc[(size_t)(row0 + 2*lane    )*32 + h]) + bi;
    float d1 = bf2f(dtc[(size_t)(row0 + 2*lane + 1)*32 + h]) + bi;
    d0 = (d0 > 20.f) ? d0 : log1pf(__expf(d0));
    d1 = (d1 > 20.f) ? d1 : log1pf(__expf(d1));
    float p = d0 + d1;
#pragma unroll
    for (int o = 1; o < 64; o <<= 1){
      float tp = __shfl_up(p, o);
      if (lane >= o) p += tp;
    }
    float cs127 = __shfl(p, 63);
    sG[2*lane    ] = __expf(Ah*(cs127 - (p - d1))) * d0;
    sG[2*lane + 1] = __expf(Ah*(cs127 - p)) * d1;
    if (lane == 0) Dcb[sci] = __expf(Ah*cs127);
  }
  __syncthreads();
  {
    const ushort* xsrc = xhT + (size_t)(b*2048 + h*64)*1024 + c*128;
    for (int q = tid; q < 1024; q += 256){
      int r = q >> 4, cc = q & 15;
      ushort8 v = *(const ushort8*)(xsrc + (size_t)r*1024 + cc*8);
      ushort8 o;
#pragma unroll
      for (int j = 0; j < 8; ++j) o[j] = f2bf(bf2f(v[j]) * sG[cc*8 + j]);
      *(ushort8*)&sXG[r*128 + ((cc ^ (r & 7))*8)] = o;
    }
  }
  __syncthreads();
  f32x4 acc[4][2];
#pragma unroll
  for (int m=0;m<4;m++)
#pragma unroll
    for (int nf=0;nf<2;nf++) acc[m][nf] = (f32x4){0.f,0.f,0.f,0.f};
  for (int ks = 0; ks < 4; ++ks){
    bf16x8 av[4], bv[2];
#pragma unroll
    for (int m = 0; m < 4; ++m){
      int rp = m*16 + l16;
      av[m] = *(const bf16x8*)&sXG[rp*128 + (((ks*4 + l4) ^ (rp & 7))*8)];
    }
#pragma unroll
    for (int nf = 0; nf < 2; ++nf){
      int rn = wave*32 + nf*16 + l16;
      bv[nf] = *(const bf16x8*)&sBT[rn*128 + (((ks*4 + l4) ^ (rn & 7))*8)];
    }
#pragma unroll
    for (int m = 0; m < 4; ++m)
#pragma unroll
      for (int nf = 0; nf < 2; ++nf)
        acc[m][nf] = __builtin_amdgcn_mfma_f32_16x16x32_bf16(av[m], bv[nf], acc[m][nf], 0, 0, 0);
  }
  const size_t base = (size_t)sci * 8192;
#pragma unroll
  for (int m = 0; m < 4; ++m)
#pragma unroll
    for (int nf = 0; nf < 2; ++nf)
#pragma unroll
      for (int r = 0; r < 4; ++r){
        int p = m*16 + l4*4 + r;
        int n = wave*32 + nf*16 + l16;
        Sc[base + p*128 + n] = f2bf(acc[m][nf][r]);
      }
}

// ---------------- chunk recurrence: h <- h*Dc + Sc ; writes h_in over Sc in place ----------------
__global__ __launch_bounds__(256) void k_chunkscan(ushort* __restrict__ Sc,
                                                   const float* __restrict__ Dcb){
  size_t idx = (size_t)blockIdx.x*256 + threadIdx.x;   // 2,097,152 total
  int bh = (int)(idx >> 13);
  int pn = (int)(idx & 8191);
  float hv = 0.f;
  for (int c = 0; c < 8; ++c){
    size_t o = (size_t)(bh*8 + c)*8192 + pn;
    float s = bf2f(Sc[o]);
    float dc = Dcb[bh*8 + c];
    Sc[o] = f2bf(hv);
    hv = hv*dc + s;
  }
}

// ---------------- main SSD chunk kernel: y = (mask.(C@B^T))@X + decay*(C@h^T), gated ----------------
__global__ __launch_bounds__(256) void k_ssd(
    const ushort* __restrict__ co, const ushort* __restrict__ zz,
    const ushort* __restrict__ dtc, const ushort* __restrict__ xhT,
    const ushort* __restrict__ Hin,
    const float* __restrict__ dt_bias, const float* __restrict__ A_log,
    const float* __restrict__ D_param,
    ushort* __restrict__ yv){
  __shared__ __align__(16) ushort sC [128*128];  // 32KB C tile (swizzled)
  __shared__ __align__(16) ushort sBP[128*128];  // 32KB B tile, then P (swizzled)
  __shared__ __align__(16) ushort sXT[64*128];   // 16KB x^T tile (swizzled)
  __shared__ __align__(16) ushort sH [64*128];   // 16KB h_in (swizzled)
  __shared__ float csv[128], dtv[128];
  const int bid = blockIdx.x;
  const int h = bid & 31, bc = bid >> 5, b = bc >> 3, c = bc & 7;
  const int tid = threadIdx.x, wave = tid >> 6, lane = tid & 63;
  const int l16 = lane & 15, l4 = lane >> 4;
  const int row0 = b*1024 + c*128;
  const ushort* cbase = co + (size_t)row0*CONVDIM;
  for (int i2 = 0; i2 < 8; ++i2){
    int itg = wave*8 + i2;
    int r = itg*4 + l4;
    int cc = l16 ^ (r & 7);
    gload16(cbase + (size_t)r*CONVDIM + 2176 + cc*8, &sC [itg*512]);
    gload16(cbase + (size_t)r*CONVDIM + 2048 + cc*8, &sBP[itg*512]);
  }
  {
    const ushort* xsrc = xhT + (size_t)(b*2048 + h*64)*1024 + c*128;
    const size_t hbase = (size_t)((b*32 + h)*8 + c)*8192;
    for (int i2 = 0; i2 < 4; ++i2){
      int itg = wave*4 + i2;
      int r = itg*4 + l4;
      int cc = l16 ^ (r & 7);
      gload16(xsrc + (size_t)r*1024 + cc*8, &sXT[itg*512]);
      gload16(Hin + hbase + r*128 + cc*8, &sH[itg*512]);
    }
  }
  const float Ah = -__expf(A_log[h]);
  if (wave == 0){
    float bi = dt_bias[h];
    float d0 = bf2f(dtc[(size_t)(row0 + 2*lane    )*32 + h]) + bi;
    float d1 = bf2f(dtc[(size_t)(row0 + 2*lane + 1)*32 + h]) + bi;
    d0 = (d0 > 20.f) ? d0 : log1pf(__expf(d0));
    d1 = (d1 > 20.f) ? d1 : log1pf(__expf(d1));
    float p = d0 + d1;
#pragma unroll
    for (int o = 1; o < 64; o <<= 1){
      float tp = __shfl_up(p, o);
      if (lane >= o) p += tp;
    }
    csv[2*lane    ] = p - d1;
    csv[2*lane + 1] = p;
    dtv[2*lane    ] = d0;
    dtv[2*lane + 1] = d1;
  }
  __syncthreads();
  const int wr = wave >> 1, wc = wave & 1;
  // GEMM1: S[i][s] = C[i].B[s]
  f32x4 acc[4][4];
#pragma unroll
  for (int m=0;m<4;m++)
#pragma unroll
    for (int n=0;n<4;n++) acc[m][n] = (f32x4){0.f,0.f,0.f,0.f};
  for (int ks = 0; ks < 4; ++ks){
    bf16x8 av[4], bv[4];
#pragma unroll
    for (int m = 0; m < 4; ++m){
      int ri = wr*64 + m*16 + l16;
      av[m] = *(const bf16x8*)&sC[ri*128 + (((ks*4 + l4) ^ (ri & 7))*8)];
    }
#pragma unroll
    for (int n = 0; n < 4; ++n){
      int rs = wc*64 + n*16 + l16;
      bv[n] = *(const bf16x8*)&sBP[rs*128 + (((ks*4 + l4) ^ (rs & 7))*8)];
    }
#pragma unroll
    for (int m = 0; m < 4; ++m)
#pragma unroll
      for (int n = 0; n < 4; ++n)
        acc[m][n] = __builtin_amdgcn_mfma_f32_16x16x32_bf16(av[m], bv[n], acc[m][n], 0, 0, 0);
  }
  __syncthreads();
  // mask + dt + D-diagonal -> P (bf16, over B tile)
  const float Dp = D_param[h];
#pragma unroll
  for (int m = 0; m < 4; ++m){
#pragma unroll
    for (int r = 0; r < 4; ++r){
      int i = wr*64 + m*16 + l4*4 + r;
      float ci = csv[i];
#pragma unroll
      for (int n = 0; n < 4; ++n){
        int s = wc*64 + n*16 + l16;
        float e = __expf(Ah*(ci - csv[s]));
        float v = (i >= s) ? acc[m][n][r]*e*dtv[s] : 0.f;
        if (i == s) v += Dp;
        sBP[i*128 + (s ^ ((i & 7)<<3))] = f2bf(v);
      }
    }
  }
  __syncthreads();
  // GEMM2: Y[i][p] = P@X^T + Ei*(C@h^T)
  f32x4 accY[4][2], accI[4][2];
#pragma unroll
  for (int m=0;m<4;m++)
#pragma unroll
    for (int n=0;n<2;n++){ accY[m][n] = (f32x4){0.f,0.f,0.f,0.f}; accI[m][n] = (f32x4){0.f,0.f,0.f,0.f}; }
  for (int ks = 0; ks < 4; ++ks){
    bf16x8 pa[4], ca[4], xb[2], hb[2];
#pragma unroll
    for (int m = 0; m < 4; ++m){
      int ri = wr*64 + m*16 + l16;
      int off = ((ks*4 + l4) ^ (ri & 7))*8;
      pa[m] = *(const bf16x8*)&sBP[ri*128 + off];
      ca[m] = *(const bf16x8*)&sC [ri*128 + off];
    }
#pragma unroll
    for (int n = 0; n < 2; ++n){
      int rp = wc*32 + n*16 + l16;
      int off = ((ks*4 + l4) ^ (rp & 7))*8;
      xb[n] = *(const bf16x8*)&sXT[rp*128 + off];
      hb[n] = *(const bf16x8*)&sH [rp*128 + off];
    }
#pragma unroll
    for (int m = 0; m < 4; ++m)
#pragma unroll
      for (int n = 0; n < 2; ++n){
        accY[m][n] = __builtin_amdgcn_mfma_f32_16x16x32_bf16(pa[m], xb[n], accY[m][n], 0, 0, 0);
        accI[m][n] = __builtin_amdgcn_mfma_f32_16x16x32_bf16(ca[m], hb[n], accI[m][n], 0, 0, 0);
      }
  }
#pragma unroll
  for (int m = 0; m < 4; ++m){
#pragma unroll
    for (int r = 0; r < 4; ++r){
      int i = wr*64 + m*16 + l4*4 + r;
      float Ei = __expf(Ah*csv[i]);
      int grow = row0 + i;
#pragma unroll
      for (int n = 0; n < 2; ++n){
        int p = wc*32 + n*16 + l16;
        float yvl = accY[m][n][r] + Ei*accI[m][n][r];
        float z = bf2f(zz[(size_t)grow*2048 + h*64 + p]);
        yv[(size_t)grow*DI + h*64 + p] = f2bf(yvl * siluf(z));
      }
    }
  }
}

extern "C" void kernel_launch(void* const* d_in, const int* in_sizes, int n_in,
                              void* d_out, int out_size, void* d_ws, size_t ws_size,
                              hipStream_t stream){
  const float* x       = (const float*)d_in[0];
  const float* t       = (const float*)d_in[1];
  const float* y       = (const float*)d_in[2];
  const float* w_ada   = (const float*)d_in[3];
  const float* b_ada   = (const float*)d_in[4];
  const float* w_in    = (const float*)d_in[5];
  const float* conv_w  = (const float*)d_in[6];
  const float* conv_b  = (const float*)d_in[7];
  const float* dt_bias = (const float*)d_in[8];
  const float* A_log   = (const float*)d_in[9];
  const float* D_param = (const float*)d_in[10];
  const float* w_out   = (const float*)d_in[11];

  char* w = (char*)d_ws;
  size_t off = 0;
  auto alloc = [&](size_t bytes)->char*{
    char* p = w + off; off += (bytes + 255) & ~(size_t)255; return p;
  };
  ushort* zz    = (ushort*)alloc((size_t)ROWS*2048*2);   // z part of in_proj
  ushort* xbc   = (ushort*)alloc((size_t)ROWS*CONVDIM*2);// conv input; xhT alias (33.6<=37.7MB)
  ushort* dtc   = (ushort*)alloc((size_t)ROWS*32*2);     // dt logits
  ushort* co    = (ushort*)alloc((size_t)ROWS*CONVDIM*2);
  ushort* Mss   = (ushort*)alloc((size_t)ROWS*2048*2);   // shift|scale -> Sc alias
  ushort* Mg    = (ushort*)alloc((size_t)ROWS*1024*2);   // gate
  ushort* yv    = (ushort*)alloc((size_t)ROWS*DI*2);
  ushort* woutT = (ushort*)alloc(1024ull*2048*2);
  ushort* waT   = (ushort*)alloc(3072ull*1024*2);
  ushort* winT  = (ushort*)alloc(4384ull*1024*2);
  float*  atb   = (float*) alloc(8ull*3072*4);
  ushort* Ya    = (ushort*)alloc((size_t)ROWS*1024*2);   // silu(y) -> mod
  ushort* BTg   = (ushort*)alloc((size_t)8*128*1024*2);
  float*  Dcb   = (float*) alloc(2048ull*4);
  ushort* xhT   = xbc;   // alias: xbc dead after k_conv; xhT needs 33.6MB <= 37.7MB
  ushort* Sc    = Mss;   // alias: Mss dead after k_lnmod; same size (33.6MB)

  // 1. Ya = bf16(silu(y))
  k_silu_cast<<<dim3(ROWS*1024/(256*4)), 256, 0, stream>>>(y, Ya, ROWS*1024);
  // 2. weight transposes (f32 -> bf16 [N][K])
  k_transpose_cast<<<dim3(96,32),  256, 0, stream>>>(w_ada, waT,  1024, 3072);
  k_transpose_cast<<<dim3(137,32), 256, 0, stream>>>(w_in,  winT, 1024, 4384);
  k_transpose_cast<<<dim3(32,64),  256, 0, stream>>>(w_out, woutT, 2048, 1024);
  // 3. at = silu(t)@w_ada + b_ada  (f32)
  k_at<<<dim3(12,8), 256, 0, stream>>>(t, w_ada, b_ada, atb);
  // 4. [shift|scale] -> Mss, gate -> Mg
  k_gemm<1><<<dim3(24,64), 256, 0, stream>>>(Ya, waT, Mss, Mg, nullptr, nullptr, ROWS, 3072, 1024,
                                             b_ada, atb, nullptr, nullptr);
  // 5. mod = LN(x)*(1+scale)+shift  (into Ya)
  k_lnmod<<<dim3(ROWS), 256, 0, stream>>>(x, Mss, Ya);
  // 6. in_proj: zz | xbc | dtc
  k_gemm<0><<<dim3(35,64), 256, 0, stream>>>(Ya, winT, zz, xbc, dtc, nullptr, ROWS, DPROJ, 1024,
                                             nullptr, nullptr, nullptr, nullptr);
  // 7. conv4 + silu
  k_conv<<<dim3(9,ROWS), 256, 0, stream>>>(xbc, conv_w, conv_b, co);
  // 8. transpose xh+B -> xhT (over xbc), BTg
  k_transT<<<dim3(34,16,8), 256, 0, stream>>>(co, xhT, BTg);
  // 9. per-chunk state contributions (Sc over Mss)
  k_chunkstate<<<dim3(2048), 256, 0, stream>>>(xhT, BTg, dtc, dt_bias, A_log, Sc, Dcb);
  // 10. chunk-state recurrence (in place: Sc -> h_in)
  k_chunkscan<<<dim3(8192), 256, 0, stream>>>(Sc, Dcb);
  // 11. SSD main: intra + inter + D + silu(z) gate -> yv
  k_ssd<<<dim3(2048), 256, 0, stream>>>(co, zz, dtc, xhT, Sc, dt_bias, A_log, D_param, yv);
  // 12. out = gate * (yv @ w_out) + x
  k_gemm<2><<<dim3(8,64), 256, 0, stream>>>(yv, woutT, nullptr, nullptr, nullptr, (float*)d_out,
                                            ROWS, 1024, 2048, nullptr, nullptr, Mg, x);
}

// Round 4
// 565.829 us; speedup vs baseline: 2.4599x; 1.0004x over previous
//
#include <hip/hip_runtime.h>

typedef float f32x4 __attribute__((ext_vector_type(4)));
typedef __bf16 bf16x8 __attribute__((ext_vector_type(8)));
typedef unsigned short ushort;
typedef ushort ushort8 __attribute__((ext_vector_type(8)));
typedef ushort ushort4v __attribute__((ext_vector_type(4)));

#define DM 1024
#define DI 2048
#define DSTATE 128
#define NH 32
#define HD 64
#define CONVDIM 2304
#define DPROJ 4384
#define ROWS 8192

__device__ __forceinline__ float bf2f(ushort u){
  union { unsigned int i; float f; } v; v.i = ((unsigned int)u)<<16; return v.f;
}
__device__ __forceinline__ ushort f2bf(float f){
  union { float f; unsigned int i; } v; v.f = f;
  unsigned int r = v.i + 0x7FFFu + ((v.i>>16)&1u);
  return (ushort)(r>>16);
}
__device__ __forceinline__ float siluf(float x){ return x / (1.f + __expf(-x)); }

__device__ __forceinline__ void gload16(const ushort* g, ushort* l){
  __builtin_amdgcn_global_load_lds(
      (const __attribute__((address_space(1))) void*)g,
      (__attribute__((address_space(3))) void*)l, 16, 0, 0);
}

// ---------------- elementwise: Ya = bf16(silu(y)) ----------------
__global__ __launch_bounds__(256) void k_silu_cast(const float* __restrict__ in,
                                                   ushort* __restrict__ out, int n){
  int i = (blockIdx.x*256 + threadIdx.x)*4;
  if (i >= n) return;
  float4 v = *(const float4*)(in + i);
  ushort4v o;
  o.x = f2bf(siluf(v.x)); o.y = f2bf(siluf(v.y));
  o.z = f2bf(siluf(v.z)); o.w = f2bf(siluf(v.w));
  *(ushort4v*)(out + i) = o;
}

// ---------------- weight transpose+cast: in[K][N] f32 -> out[N][K] bf16 ----------------
__global__ __launch_bounds__(256) void k_transpose_cast(const float* __restrict__ in,
                                                        ushort* __restrict__ out,
                                                        int K, int N){
  __shared__ float tile[32][33];
  int n0 = blockIdx.x*32, k0 = blockIdx.y*32;
  int tx = threadIdx.x & 31, ty = threadIdx.x >> 5; // 32x8
  for (int r = ty; r < 32; r += 8) tile[r][tx] = in[(size_t)(k0+r)*N + n0+tx];
  __syncthreads();
  for (int r = ty; r < 32; r += 8) out[(size_t)(n0+r)*K + k0+tx] = f2bf(tile[tx][r]);
}

// ---------------- at[b][n] = silu(t[b]) @ w_ada + b_ada ----------------
__global__ __launch_bounds__(256) void k_at(const float* __restrict__ t,
                                            const float* __restrict__ w_ada,
                                            const float* __restrict__ b_ada,
                                            float* __restrict__ at){
  __shared__ float st[1024];
  int b = blockIdx.y;
  int col = blockIdx.x*256 + threadIdx.x;
  for (int i = threadIdx.x; i < 1024; i += 256) st[i] = siluf(t[b*1024 + i]);
  __syncthreads();
  float acc = 0.f;
  for (int k = 0; k < 1024; ++k) acc += st[k] * w_ada[(size_t)k*3072 + col];
  at[b*3072 + col] = acc + b_ada[col];
}

// ---------------- GEMM: A[M][K] bf16 row-major, Bt[N][K] bf16 row-major ----------------
// LDS tile [128 rows][4 chunks of 8 ushorts]; chunk swizzled: chunk_lds = k_chunk ^ ((row>>1)&3)
// EPI 0: in_proj -> zz (cols<2048), xbc (2048..4352), dtc (4352..)
// EPI 1: ada -> Mss (cols<2048: shift|scale), Mg (cols>=2048: gate)
// EPI 2: Cf f32 = gate[row,n]*acc + x[row,n]
template<int EPI>
__global__ __launch_bounds__(256)
void k_gemm(const ushort* __restrict__ A, const ushort* __restrict__ Bt,
            ushort* __restrict__ Cb, ushort* __restrict__ Cb2, ushort* __restrict__ Cb3,
            float* __restrict__ Cf,
            int M, int N, int K,
            const float* __restrict__ bias, const float* __restrict__ at,
            const ushort* __restrict__ gateM, const float* __restrict__ xres){
  __shared__ __align__(16) ushort lA[128*32];
  __shared__ __align__(16) ushort lB[128*32];
  const int tid  = threadIdx.x;
  const int wave = tid >> 6, lane = tid & 63;
  const int bn = blockIdx.x, bm = blockIdx.y;
  const int wr = wave >> 1, wc = wave & 1;
  const int l16 = lane & 15, kb = lane >> 4;
  const int arow0 = (wave*2+0)*16 + (lane>>2);
  const int arow1 = (wave*2+1)*16 + (lane>>2);
  // swizzled staging column: kc ^ ((row>>1)&3) with row = itg*16 + (lane>>2)
  const int kcs = (lane & 3) ^ ((lane>>3)&3);
  // swizzled read chunk: kb ^ ((row>>1)&3) with row = base + l16
  const int kbs = (kb ^ ((l16>>1)&3))*8;

  f32x4 acc[4][4];
#pragma unroll
  for (int m=0;m<4;m++)
#pragma unroll
    for (int n=0;n<4;n++) acc[m][n] = (f32x4){0.f,0.f,0.f,0.f};

  for (int k0 = 0; k0 < K; k0 += 32){
    __syncthreads();
    {
      gload16(A + (size_t)(bm*128 + arow0)*K + k0 + kcs*8, &lA[(wave*2+0)*512]);
      gload16(A + (size_t)(bm*128 + arow1)*K + k0 + kcs*8, &lA[(wave*2+1)*512]);
      int br0 = bn*128 + arow0; if (br0 > N-1) br0 = N-1;
      int br1 = bn*128 + arow1; if (br1 > N-1) br1 = N-1;
      gload16(Bt + (size_t)br0*K + k0 + kcs*8, &lB[(wave*2+0)*512]);
      gload16(Bt + (size_t)br1*K + k0 + kcs*8, &lB[(wave*2+1)*512]);
    }
    __syncthreads();
    bf16x8 af[4], bfr[4];
#pragma unroll
    for (int m=0;m<4;m++) af[m]  = *(const bf16x8*)&lA[(wr*64 + m*16 + l16)*32 + kbs];
#pragma unroll
    for (int n=0;n<4;n++) bfr[n] = *(const bf16x8*)&lB[(wc*64 + n*16 + l16)*32 + kbs];
#pragma unroll
    for (int m=0;m<4;m++)
#pragma unroll
      for (int n=0;n<4;n++)
        acc[m][n] = __builtin_amdgcn_mfma_f32_16x16x32_bf16(af[m], bfr[n], acc[m][n], 0, 0, 0);
  }

#pragma unroll
  for (int m=0;m<4;m++){
    int grow_base = bm*128 + wr*64 + m*16 + (lane>>4)*4;
#pragma unroll
    for (int n=0;n<4;n++){
      int gcol = bn*128 + wc*64 + n*16 + l16;
      if (EPI == 0){
        if (gcol < N){
#pragma unroll
          for (int r=0;r<4;r++){
            int row = grow_base + r;
            float v = acc[m][n][r];
            if (gcol < 2048)      Cb [(size_t)row*2048 + gcol] = f2bf(v);
            else if (gcol < 4352) Cb2[(size_t)row*2304 + (gcol-2048)] = f2bf(v);
            else                  Cb3[(size_t)row*32   + (gcol-4352)] = f2bf(v);
          }
        }
      } else if (EPI == 1){
        float bv = bias[gcol];
#pragma unroll
        for (int r=0;r<4;r++){
          int row = grow_base + r;
          float v = acc[m][n][r] + bv + at[(row>>10)*3072 + gcol];
          if (gcol < 2048) Cb [(size_t)row*2048 + gcol] = f2bf(v);
          else             Cb2[(size_t)row*1024 + (gcol - 2048)] = f2bf(v);
        }
      } else {
#pragma unroll
        for (int r=0;r<4;r++){
          int row = grow_base + r;
          float g = bf2f(gateM[(size_t)row*1024 + gcol]);
          Cf[(size_t)row*1024 + gcol] = g*acc[m][n][r] + xres[(size_t)row*1024 + gcol];
        }
      }
    }
  }
}

// ---------------- LN + modulation: mod = LN(x)*(1+scale)+shift (bf16) ----------------
__global__ __launch_bounds__(256) void k_lnmod(const float* __restrict__ x,
                                               const ushort* __restrict__ Mss,
                                               ushort* __restrict__ mod){
  int row = blockIdx.x;
  const float* xr = x + (size_t)row*1024;
  float v[4]; float s = 0.f, s2 = 0.f;
#pragma unroll
  for (int j=0;j<4;j++){ v[j] = xr[threadIdx.x + j*256]; s += v[j]; s2 += v[j]*v[j]; }
#pragma unroll
  for (int o=32;o>0;o>>=1){ s += __shfl_down(s,o); s2 += __shfl_down(s2,o); }
  __shared__ float ls[4], ls2[4];
  int wv = threadIdx.x >> 6;
  if ((threadIdx.x & 63) == 0){ ls[wv] = s; ls2[wv] = s2; }
  __syncthreads();
  s  = ls[0]+ls[1]+ls[2]+ls[3];
  s2 = ls2[0]+ls2[1]+ls2[2]+ls2[3];
  float mu = s * (1.f/1024.f);
  float var = s2 * (1.f/1024.f) - mu*mu;
  float rstd = rsqrtf(var + 1e-6f);
  const ushort* Mr = Mss + (size_t)row*2048;
#pragma unroll
  for (int j=0;j<4;j++){
    int d = threadIdx.x + j*256;
    float sc = bf2f(Mr[1024 + d]);
    float sh = bf2f(Mr[d]);
    mod[(size_t)row*1024 + d] = f2bf((v[j]-mu)*rstd*(1.f+sc) + sh);
  }
}

// ---------------- causal conv4 + silu over xbc ----------------
__global__ __launch_bounds__(256) void k_conv(const ushort* __restrict__ xbc,
                                              const float* __restrict__ conv_w,
                                              const float* __restrict__ conv_b,
                                              ushort* __restrict__ co){
  int ch  = blockIdx.x*256 + threadIdx.x;   // < 2304
  int row = blockIdx.y;                      // < 8192
  int l = row & 1023, b = row >> 10;
  float acc = conv_b[ch];
#pragma unroll
  for (int k=0;k<4;k++){
    int ll = l - 3 + k;
    if (ll >= 0) acc += conv_w[ch*4 + k] * bf2f(xbc[(size_t)(b*1024 + ll)*CONVDIM + ch]);
  }
  co[(size_t)row*CONVDIM + ch] = f2bf(siluf(acc));
}

// ---------------- transpose co cols [0,2176) -> xhT [b*2048+c][l], BTg [b*128+n][l] ----------------
__global__ __launch_bounds__(256) void k_transT(const ushort* __restrict__ co,
                                                ushort* __restrict__ xhT,
                                                ushort* __restrict__ BTg){
  __shared__ ushort tile[64*72];
  const int c0 = blockIdx.x*64, l0 = blockIdx.y*64, b = blockIdx.z;
  const int tid = threadIdx.x;
  for (int q = tid; q < 512; q += 256){
    int r = q >> 3, cc = q & 7;
    ushort8 v = *(const ushort8*)(co + (size_t)(b*1024 + l0 + r)*CONVDIM + c0 + cc*8);
    *(ushort8*)&tile[r*72 + cc*8] = v;
  }
  __syncthreads();
  for (int q = tid; q < 1024; q += 256){
    int oc = q >> 4, lc = (q & 15)*4;
    ushort4v o;
#pragma unroll
    for (int j = 0; j < 4; ++j) o[j] = tile[(lc + j)*72 + oc];
    int ccol = c0 + oc;
    ushort* out = (ccol < 2048) ? (xhT + (size_t)(b*2048 + ccol)*1024)
                                : (BTg + (size_t)(b*128 + (ccol - 2048))*1024);
    *(ushort4v*)(out + l0 + lc) = o;
  }
}

// ---------------- chunk state contribution: Sc[p][n] = sum_s G[s]*x[s,p]*B[s,n] ----------------
__global__ __launch_bounds__(256) void k_chunkstate(
    const ushort* __restrict__ xhT, const ushort* __restrict__ BTg,
    const ushort* __restrict__ dtc,
    const float* __restrict__ dt_bias, const float* __restrict__ A_log,
    ushort* __restrict__ Sc, float* __restrict__ Dcb){
  __shared__ __align__(16) ushort sXG[64*128];   // 16KB (swizzled)
  __shared__ __align__(16) ushort sBT[128*128];  // 32KB (swizzled)
  __shared__ float sG[128];
  const int bid = blockIdx.x;
  const int h = bid & 31, bc = bid >> 5, b = bc >> 3, c = bc & 7;
  const int tid = threadIdx.x, wave = tid >> 6, lane = tid & 63;
  const int l16 = lane & 15, l4 = lane >> 4;
  const int sci = (b*32 + h)*8 + c;
  {
    const ushort* src = BTg + (size_t)(b*128)*1024 + c*128;
    for (int i2 = 0; i2 < 8; ++i2){
      int itg = wave*8 + i2;
      int r = itg*4 + l4;
      int cc = l16 ^ (r & 7);
      gload16(src + (size_t)r*1024 + cc*8, &sBT[itg*512]);
    }
  }
  const float Ah = -__expf(A_log[h]);
  if (wave == 0){
    const int row0 = b*1024 + c*128;
    float bi = dt_bias[h];
    float d0 = bf2f(dtc[(size_t)(row0 + 2*lane    )*32 + h]) + bi;
    float d1 = bf2f(dtc[(size_t)(row0 + 2*lane + 1)*32 + h]) + bi;
    d0 = (d0 > 20.f) ? d0 : log1pf(__expf(d0));
    d1 = (d1 > 20.f) ? d1 : log1pf(__expf(d1));
    float p = d0 + d1;
#pragma unroll
    for (int o = 1; o < 64; o <<= 1){
      float tp = __shfl_up(p, o);
      if (lane >= o) p += tp;
    }
    float cs127 = __shfl(p, 63);
    sG[2*lane    ] = __expf(Ah*(cs127 - (p - d1))) * d0;
    sG[2*lane + 1] = __expf(Ah*(cs127 - p)) * d1;
    if (lane == 0) Dcb[sci] = __expf(Ah*cs127);
  }
  __syncthreads();
  {
    const ushort* xsrc = xhT + (size_t)(b*2048 + h*64)*1024 + c*128;
    for (int q = tid; q < 1024; q += 256){
      int r = q >> 4, cc = q & 15;
      ushort8 v = *(const ushort8*)(xsrc + (size_t)r*1024 + cc*8);
      ushort8 o;
#pragma unroll
      for (int j = 0; j < 8; ++j) o[j] = f2bf(bf2f(v[j]) * sG[cc*8 + j]);
      *(ushort8*)&sXG[r*128 + ((cc ^ (r & 7))*8)] = o;
    }
  }
  __syncthreads();
  f32x4 acc[4][2];
#pragma unroll
  for (int m=0;m<4;m++)
#pragma unroll
    for (int nf=0;nf<2;nf++) acc[m][nf] = (f32x4){0.f,0.f,0.f,0.f};
  for (int ks = 0; ks < 4; ++ks){
    bf16x8 av[4], bv[2];
#pragma unroll
    for (int m = 0; m < 4; ++m){
      int rp = m*16 + l16;
      av[m] = *(const bf16x8*)&sXG[rp*128 + (((ks*4 + l4) ^ (rp & 7))*8)];
    }
#pragma unroll
    for (int nf = 0; nf < 2; ++nf){
      int rn = wave*32 + nf*16 + l16;
      bv[nf] = *(const bf16x8*)&sBT[rn*128 + (((ks*4 + l4) ^ (rn & 7))*8)];
    }
#pragma unroll
    for (int m = 0; m < 4; ++m)
#pragma unroll
      for (int nf = 0; nf < 2; ++nf)
        acc[m][nf] = __builtin_amdgcn_mfma_f32_16x16x32_bf16(av[m], bv[nf], acc[m][nf], 0, 0, 0);
  }
  const size_t base = (size_t)sci * 8192;
#pragma unroll
  for (int m = 0; m < 4; ++m)
#pragma unroll
    for (int nf = 0; nf < 2; ++nf)
#pragma unroll
      for (int r = 0; r < 4; ++r){
        int p = m*16 + l4*4 + r;
        int n = wave*32 + nf*16 + l16;
        Sc[base + p*128 + n] = f2bf(acc[m][nf][r]);
      }
}

// ---------------- chunk recurrence: h <- h*Dc + Sc ; writes h_in over Sc in place ----------------
__global__ __launch_bounds__(256) void k_chunkscan(ushort* __restrict__ Sc,
                                                   const float* __restrict__ Dcb){
  size_t idx = (size_t)blockIdx.x*256 + threadIdx.x;   // 2,097,152 total
  int bh = (int)(idx >> 13);
  int pn = (int)(idx & 8191);
  float hv = 0.f;
  for (int c = 0; c < 8; ++c){
    size_t o = (size_t)(bh*8 + c)*8192 + pn;
    float s = bf2f(Sc[o]);
    float dc = Dcb[bh*8 + c];
    Sc[o] = f2bf(hv);
    hv = hv*dc + s;
  }
}

// ---------------- main SSD chunk kernel: y = (mask.(C@B^T))@X + decay*(C@h^T), gated ----------------
__global__ __launch_bounds__(256) void k_ssd(
    const ushort* __restrict__ co, const ushort* __restrict__ zz,
    const ushort* __restrict__ dtc, const ushort* __restrict__ xhT,
    const ushort* __restrict__ Hin,
    const float* __restrict__ dt_bias, const float* __restrict__ A_log,
    const float* __restrict__ D_param,
    ushort* __restrict__ yv){
  __shared__ __align__(16) ushort sC [128*128];  // 32KB C tile (swizzled)
  __shared__ __align__(16) ushort sBP[128*128];  // 32KB B tile, then P (swizzled)
  __shared__ __align__(16) ushort sXT[64*128];   // 16KB x^T tile (swizzled)
  __shared__ __align__(16) ushort sH [64*128];   // 16KB h_in (swizzled)
  __shared__ float csv[128], dtv[128];
  const int bid = blockIdx.x;
  const int h = bid & 31, bc = bid >> 5, b = bc >> 3, c = bc & 7;
  const int tid = threadIdx.x, wave = tid >> 6, lane = tid & 63;
  const int l16 = lane & 15, l4 = lane >> 4;
  const int row0 = b*1024 + c*128;
  const ushort* cbase = co + (size_t)row0*CONVDIM;
  for (int i2 = 0; i2 < 8; ++i2){
    int itg = wave*8 + i2;
    int r = itg*4 + l4;
    int cc = l16 ^ (r & 7);
    gload16(cbase + (size_t)r*CONVDIM + 2176 + cc*8, &sC [itg*512]);
    gload16(cbase + (size_t)r*CONVDIM + 2048 + cc*8, &sBP[itg*512]);
  }
  {
    const ushort* xsrc = xhT + (size_t)(b*2048 + h*64)*1024 + c*128;
    const size_t hbase = (size_t)((b*32 + h)*8 + c)*8192;
    for (int i2 = 0; i2 < 4; ++i2){
      int itg = wave*4 + i2;
      int r = itg*4 + l4;
      int cc = l16 ^ (r & 7);
      gload16(xsrc + (size_t)r*1024 + cc*8, &sXT[itg*512]);
      gload16(Hin + hbase + r*128 + cc*8, &sH[itg*512]);
    }
  }
  const float Ah = -__expf(A_log[h]);
  if (wave == 0){
    float bi = dt_bias[h];
    float d0 = bf2f(dtc[(size_t)(row0 + 2*lane    )*32 + h]) + bi;
    float d1 = bf2f(dtc[(size_t)(row0 + 2*lane + 1)*32 + h]) + bi;
    d0 = (d0 > 20.f) ? d0 : log1pf(__expf(d0));
    d1 = (d1 > 20.f) ? d1 : log1pf(__expf(d1));
    float p = d0 + d1;
#pragma unroll
    for (int o = 1; o < 64; o <<= 1){
      float tp = __shfl_up(p, o);
      if (lane >= o) p += tp;
    }
    csv[2*lane    ] = p - d1;
    csv[2*lane + 1] = p;
    dtv[2*lane    ] = d0;
    dtv[2*lane + 1] = d1;
  }
  __syncthreads();
  const int wr = wave >> 1, wc = wave & 1;
  // GEMM1: S[i][s] = C[i].B[s]
  f32x4 acc[4][4];
#pragma unroll
  for (int m=0;m<4;m++)
#pragma unroll
    for (int n=0;n<4;n++) acc[m][n] = (f32x4){0.f,0.f,0.f,0.f};
  for (int ks = 0; ks < 4; ++ks){
    bf16x8 av[4], bv[4];
#pragma unroll
    for (int m = 0; m < 4; ++m){
      int ri = wr*64 + m*16 + l16;
      av[m] = *(const bf16x8*)&sC[ri*128 + (((ks*4 + l4) ^ (ri & 7))*8)];
    }
#pragma unroll
    for (int n = 0; n < 4; ++n){
      int rs = wc*64 + n*16 + l16;
      bv[n] = *(const bf16x8*)&sBP[rs*128 + (((ks*4 + l4) ^ (rs & 7))*8)];
    }
#pragma unroll
    for (int m = 0; m < 4; ++m)
#pragma unroll
      for (int n = 0; n < 4; ++n)
        acc[m][n] = __builtin_amdgcn_mfma_f32_16x16x32_bf16(av[m], bv[n], acc[m][n], 0, 0, 0);
  }
  __syncthreads();
  // mask + dt + D-diagonal -> P (bf16, over B tile)
  const float Dp = D_param[h];
#pragma unroll
  for (int m = 0; m < 4; ++m){
#pragma unroll
    for (int r = 0; r < 4; ++r){
      int i = wr*64 + m*16 + l4*4 + r;
      float ci = csv[i];
#pragma unroll
      for (int n = 0; n < 4; ++n){
        int s = wc*64 + n*16 + l16;
        float e = __expf(Ah*(ci - csv[s]));
        float v = (i >= s) ? acc[m][n][r]*e*dtv[s] : 0.f;
        if (i == s) v += Dp;
        sBP[i*128 + (s ^ ((i & 7)<<3))] = f2bf(v);
      }
    }
  }
  __syncthreads();
  // GEMM2: Y[i][p] = P@X^T + Ei*(C@h^T)
  f32x4 accY[4][2], accI[4][2];
#pragma unroll
  for (int m=0;m<4;m++)
#pragma unroll
    for (int n=0;n<2;n++){ accY[m][n] = (f32x4){0.f,0.f,0.f,0.f}; accI[m][n] = (f32x4){0.f,0.f,0.f,0.f}; }
  for (int ks = 0; ks < 4; ++ks){
    bf16x8 pa[4], ca[4], xb[2], hb[2];
#pragma unroll
    for (int m = 0; m < 4; ++m){
      int ri = wr*64 + m*16 + l16;
      int off = ((ks*4 + l4) ^ (ri & 7))*8;
      pa[m] = *(const bf16x8*)&sBP[ri*128 + off];
      ca[m] = *(const bf16x8*)&sC [ri*128 + off];
    }
#pragma unroll
    for (int n = 0; n < 2; ++n){
      int rp = wc*32 + n*16 + l16;
      int off = ((ks*4 + l4) ^ (rp & 7))*8;
      xb[n] = *(const bf16x8*)&sXT[rp*128 + off];
      hb[n] = *(const bf16x8*)&sH [rp*128 + off];
    }
#pragma unroll
    for (int m = 0; m < 4; ++m)
#pragma unroll
      for (int n = 0; n < 2; ++n){
        accY[m][n] = __builtin_amdgcn_mfma_f32_16x16x32_bf16(pa[m], xb[n], accY[m][n], 0, 0, 0);
        accI[m][n] = __builtin_amdgcn_mfma_f32_16x16x32_bf16(ca[m], hb[n], accI[m][n], 0, 0, 0);
      }
  }
#pragma unroll
  for (int m = 0; m < 4; ++m){
#pragma unroll
    for (int r = 0; r < 4; ++r){
      int i = wr*64 + m*16 + l4*4 + r;
      float Ei = __expf(Ah*csv[i]);
      int grow = row0 + i;
#pragma unroll
      for (int n = 0; n < 2; ++n){
        int p = wc*32 + n*16 + l16;
        float yvl = accY[m][n][r] + Ei*accI[m][n][r];
        float z = bf2f(zz[(size_t)grow*2048 + h*64 + p]);
        yv[(size_t)grow*DI + h*64 + p] = f2bf(yvl * siluf(z));
      }
    }
  }
}

extern "C" void kernel_launch(void* const* d_in, const int* in_sizes, int n_in,
                              void* d_out, int out_size, void* d_ws, size_t ws_size,
                              hipStream_t stream){
  const float* x       = (const float*)d_in[0];
  const float* t       = (const float*)d_in[1];
  const float* y       = (const float*)d_in[2];
  const float* w_ada   = (const float*)d_in[3];
  const float* b_ada   = (const float*)d_in[4];
  const float* w_in    = (const float*)d_in[5];
  const float* conv_w  = (const float*)d_in[6];
  const float* conv_b  = (const float*)d_in[7];
  const float* dt_bias = (const float*)d_in[8];
  const float* A_log   = (const float*)d_in[9];
  const float* D_param = (const float*)d_in[10];
  const float* w_out   = (const float*)d_in[11];

  char* w = (char*)d_ws;
  size_t off = 0;
  auto alloc = [&](size_t bytes)->char*{
    char* p = w + off; off += (bytes + 255) & ~(size_t)255; return p;
  };
  ushort* zz    = (ushort*)alloc((size_t)ROWS*2048*2);   // z part of in_proj
  ushort* xbc   = (ushort*)alloc((size_t)ROWS*CONVDIM*2);// conv input; xhT alias (33.6<=37.7MB)
  ushort* dtc   = (ushort*)alloc((size_t)ROWS*32*2);     // dt logits
  ushort* co    = (ushort*)alloc((size_t)ROWS*CONVDIM*2);
  ushort* Mss   = (ushort*)alloc((size_t)ROWS*2048*2);   // shift|scale -> Sc alias
  ushort* Mg    = (ushort*)alloc((size_t)ROWS*1024*2);   // gate
  ushort* yv    = (ushort*)alloc((size_t)ROWS*DI*2);
  ushort* woutT = (ushort*)alloc(1024ull*2048*2);
  ushort* waT   = (ushort*)alloc(3072ull*1024*2);
  ushort* winT  = (ushort*)alloc(4384ull*1024*2);
  float*  atb   = (float*) alloc(8ull*3072*4);
  ushort* Ya    = (ushort*)alloc((size_t)ROWS*1024*2);   // silu(y) -> mod
  ushort* BTg   = (ushort*)alloc((size_t)8*128*1024*2);
  float*  Dcb   = (float*) alloc(2048ull*4);
  ushort* xhT   = xbc;   // alias: xbc dead after k_conv; xhT needs 33.6MB <= 37.7MB
  ushort* Sc    = Mss;   // alias: Mss dead after k_lnmod; same size (33.6MB)

  // 1. Ya = bf16(silu(y))
  k_silu_cast<<<dim3(ROWS*1024/(256*4)), 256, 0, stream>>>(y, Ya, ROWS*1024);
  // 2. weight transposes (f32 -> bf16 [N][K])
  k_transpose_cast<<<dim3(96,32),  256, 0, stream>>>(w_ada, waT,  1024, 3072);
  k_transpose_cast<<<dim3(137,32), 256, 0, stream>>>(w_in,  winT, 1024, 4384);
  k_transpose_cast<<<dim3(32,64),  256, 0, stream>>>(w_out, woutT, 2048, 1024);
  // 3. at = silu(t)@w_ada + b_ada  (f32)
  k_at<<<dim3(12,8), 256, 0, stream>>>(t, w_ada, b_ada, atb);
  // 4. [shift|scale] -> Mss, gate -> Mg
  k_gemm<1><<<dim3(24,64), 256, 0, stream>>>(Ya, waT, Mss, Mg, nullptr, nullptr, ROWS, 3072, 1024,
                                             b_ada, atb, nullptr, nullptr);
  // 5. mod = LN(x)*(1+scale)+shift  (into Ya)
  k_lnmod<<<dim3(ROWS), 256, 0, stream>>>(x, Mss, Ya);
  // 6. in_proj: zz | xbc | dtc
  k_gemm<0><<<dim3(35,64), 256, 0, stream>>>(Ya, winT, zz, xbc, dtc, nullptr, ROWS, DPROJ, 1024,
                                             nullptr, nullptr, nullptr, nullptr);
  // 7. conv4 + silu
  k_conv<<<dim3(9,ROWS), 256, 0, stream>>>(xbc, conv_w, conv_b, co);
  // 8. transpose xh+B -> xhT (over xbc), BTg
  k_transT<<<dim3(34,16,8), 256, 0, stream>>>(co, xhT, BTg);
  // 9. per-chunk state contributions (Sc over Mss)
  k_chunkstate<<<dim3(2048), 256, 0, stream>>>(xhT, BTg, dtc, dt_bias, A_log, Sc, Dcb);
  // 10. chunk-state recurrence (in place: Sc -> h_in)
  k_chunkscan<<<dim3(8192), 256, 0, stream>>>(Sc, Dcb);
  // 11. SSD main: intra + inter + D + silu(z) gate -> yv
  k_ssd<<<dim3(2048), 256, 0, stream>>>(co, zz, dtc, xhT, Sc, dt_bias, A_log, D_param, yv);
  // 12. out = gate * (yv @ w_out) + x
  k_gemm<2><<<dim3(8,64), 256, 0, stream>>>(yv, woutT, nullptr, nullptr, nullptr, (float*)d_out,
                                            ROWS, 1024, 2048, nullptr, nullptr, Mg, x);
}